// Round 1
// baseline (323.156 us; speedup 1.0000x reference)
//
#include <hip/hip_runtime.h>

#define H 128
#define W 128
#define C 128
#define NB 4
#define HW (H * W)

// ---------------------------------------------------------------------------
// Offset conv: 3x3 SAME, 128 -> 8 channels, zero padding.
// Accumulates channels [c0,c1) into acc[8]. Weight indices are wave-uniform
// -> compiler emits scalar (SMEM) loads, no VMEM pressure.
// ---------------------------------------------------------------------------
__device__ __forceinline__ void conv8_accum(
    const float* __restrict__ xn, const float* __restrict__ wg,
    int y, int xx, int c0, int c1, float acc[8]) {
  for (int c = c0; c < c1; ++c) {
    const float* xc = xn + (size_t)c * HW;
#pragma unroll
    for (int kh = 0; kh < 3; ++kh) {
      int yy = y + kh - 1;
      float vy = ((unsigned)yy < (unsigned)H) ? 1.f : 0.f;
      int yyc = yy < 0 ? 0 : (yy > H - 1 ? H - 1 : yy);
      const float* xr = xc + yyc * W;
#pragma unroll
      for (int kw = 0; kw < 3; ++kw) {
        int xxx = xx + kw - 1;
        float vx = ((unsigned)xxx < (unsigned)W) ? 1.f : 0.f;
        int xxc = xxx < 0 ? 0 : (xxx > W - 1 ? W - 1 : xxx);
        float v = xr[xxc] * vy * vx;
#pragma unroll
        for (int p = 0; p < 8; ++p)
          acc[p] += v * wg[((p * C + c) * 3 + kh) * 3 + kw];
      }
    }
  }
}

// ---------------------------------------------------------------------------
// Bilinear sampling of channels [c0,c1) at the 4 offset points; writes the
// 2x2 output block per pixel per channel as two coalesced float2 stores.
// offv[2p] = dy, offv[2p+1] = dx for sample point p (p = kh*2+kw).
// ---------------------------------------------------------------------------
__device__ __forceinline__ void sample_store(
    const float* __restrict__ xn, float* __restrict__ outn,
    const float offv[8], int y, int xx, int c0, int c1) {
  int o00[4], o01[4], o10[4], o11[4];
  float w00[4], w01[4], w10[4], w11[4];
#pragma unroll
  for (int p = 0; p < 4; ++p) {
    float sy = (float)y + offv[2 * p];
    float sx = (float)xx + offv[2 * p + 1];
    float y0f = floorf(sy), x0f = floorf(sx);
    float wy1 = sy - y0f, wx1 = sx - x0f;
    float wy0 = 1.f - wy1, wx0 = 1.f - wx1;
    int iy0 = (int)y0f, ix0 = (int)x0f;
    int iy1 = iy0 + 1, ix1 = ix0 + 1;
    float vy0 = ((unsigned)iy0 < (unsigned)H) ? 1.f : 0.f;
    float vy1 = ((unsigned)iy1 < (unsigned)H) ? 1.f : 0.f;
    float vx0 = ((unsigned)ix0 < (unsigned)W) ? 1.f : 0.f;
    float vx1 = ((unsigned)ix1 < (unsigned)W) ? 1.f : 0.f;
    int cy0 = iy0 < 0 ? 0 : (iy0 > H - 1 ? H - 1 : iy0);
    int cy1 = iy1 < 0 ? 0 : (iy1 > H - 1 ? H - 1 : iy1);
    int cx0 = ix0 < 0 ? 0 : (ix0 > W - 1 ? W - 1 : ix0);
    int cx1 = ix1 < 0 ? 0 : (ix1 > W - 1 ? W - 1 : ix1);
    o00[p] = cy0 * W + cx0; o01[p] = cy0 * W + cx1;
    o10[p] = cy1 * W + cx0; o11[p] = cy1 * W + cx1;
    w00[p] = wy0 * wx0 * vy0 * vx0;
    w01[p] = wy0 * wx1 * vy0 * vx1;
    w10[p] = wy1 * wx0 * vy1 * vx0;
    w11[p] = wy1 * wx1 * vy1 * vx1;
  }

  for (int c = c0; c < c1; ++c) {
    const float* xc = xn + (size_t)c * HW;
    float s[4];
#pragma unroll
    for (int p = 0; p < 4; ++p) {
      s[p] = w00[p] * xc[o00[p]] + w01[p] * xc[o01[p]] +
             w10[p] * xc[o10[p]] + w11[p] * xc[o11[p]];
    }
    float* oc = outn + (size_t)c * (2 * H) * (2 * W);
    float2* r0 = (float2*)(oc + (size_t)(2 * y) * (2 * W) + 2 * xx);
    float2* r1 = (float2*)(oc + (size_t)(2 * y + 1) * (2 * W) + 2 * xx);
    *r0 = make_float2(s[0], s[1]);
    *r1 = make_float2(s[2], s[3]);
  }
}

// Thread id decode: t = ((cg*NB + n)*H + y)*W + xx
__device__ __forceinline__ void decode(int t, int& xx, int& y, int& n, int& cg) {
  xx = t & (W - 1);
  y = (t >> 7) & (H - 1);
  n = (t >> 14) & (NB - 1);
  cg = t >> 16;
}

// ---------------------------------------------------------------------------
// Kernel 1: partial offset conv. off_part layout [CG][N][8][H][W] (no bias).
// ---------------------------------------------------------------------------
__global__ __launch_bounds__(256) void conv_off_kernel(
    const float* __restrict__ x, const float* __restrict__ wg,
    float* __restrict__ off_part, int CPG) {
  int t = blockIdx.x * 256 + threadIdx.x;
  int xx, y, n, cg;
  decode(t, xx, y, n, cg);
  const float* xn = x + (size_t)n * C * HW;
  float acc[8];
#pragma unroll
  for (int p = 0; p < 8; ++p) acc[p] = 0.f;
  conv8_accum(xn, wg, y, xx, cg * CPG, cg * CPG + CPG, acc);
  float* op = off_part + ((size_t)cg * NB + n) * 8 * HW + y * W + xx;
#pragma unroll
  for (int p = 0; p < 8; ++p) op[(size_t)p * HW] = acc[p];
}

// ---------------------------------------------------------------------------
// Kernel 2: sum partials + bias, bilinear sample channel chunk, store.
// ---------------------------------------------------------------------------
__global__ __launch_bounds__(256) void sample_kernel(
    const float* __restrict__ x, const float* __restrict__ off_part,
    const float* __restrict__ b, float* __restrict__ out, int CG, int CPG) {
  int t = blockIdx.x * 256 + threadIdx.x;
  int xx, y, n, cg;
  decode(t, xx, y, n, cg);

  float offv[8];
#pragma unroll
  for (int p8 = 0; p8 < 8; ++p8) {
    float s = b[p8];
    for (int g = 0; g < CG; ++g)
      s += off_part[(((size_t)g * NB + n) * 8 + p8) * HW + y * W + xx];
    offv[p8] = s;
  }

  const float* xn = x + (size_t)n * C * HW;
  float* outn = out + (size_t)n * C * (2 * H) * (2 * W);
  sample_store(xn, outn, offv, y, xx, cg * CPG, cg * CPG + CPG);
}

// ---------------------------------------------------------------------------
// Fallback: fully fused (only if workspace is too small). One thread/pixel.
// ---------------------------------------------------------------------------
__global__ __launch_bounds__(256) void fused_kernel(
    const float* __restrict__ x, const float* __restrict__ wg,
    const float* __restrict__ b, float* __restrict__ out) {
  int t = blockIdx.x * 256 + threadIdx.x;
  int xx, y, n, cg;
  decode(t, xx, y, n, cg);
  const float* xn = x + (size_t)n * C * HW;
  float acc[8];
#pragma unroll
  for (int p = 0; p < 8; ++p) acc[p] = b[p];
  conv8_accum(xn, wg, y, xx, 0, C, acc);
  float* outn = out + (size_t)n * C * (2 * H) * (2 * W);
  sample_store(xn, outn, acc, y, xx, 0, C);
}

extern "C" void kernel_launch(void* const* d_in, const int* in_sizes, int n_in,
                              void* d_out, int out_size, void* d_ws, size_t ws_size,
                              hipStream_t stream) {
  const float* x = (const float*)d_in[0];
  const float* w = (const float*)d_in[1];
  const float* b = (const float*)d_in[2];
  float* out = (float*)d_out;

  const size_t per_group = (size_t)NB * 8 * HW * sizeof(float);  // 2 MiB
  int CG = 4;
  while (CG > 1 && per_group * (size_t)CG > ws_size) CG >>= 1;

  if (per_group * (size_t)CG <= ws_size) {
    int CPG = C / CG;
    int nthreads = NB * H * W * CG;
    dim3 grid(nthreads / 256), block(256);
    conv_off_kernel<<<grid, block, 0, stream>>>(x, w, (float*)d_ws, CPG);
    sample_kernel<<<grid, block, 0, stream>>>(x, (const float*)d_ws, b, out, CG, CPG);
  } else {
    dim3 grid(NB * H * W / 256), block(256);
    fused_kernel<<<grid, block, 0, stream>>>(x, w, b, out);
  }
}

// Round 2
// 309.425 us; speedup vs baseline: 1.0444x; 1.0444x over previous
//
#include <hip/hip_runtime.h>

#define H 128
#define W 128
#define C 128
#define NB 4
#define HW (H * W)
#define PXB 32            // pixels per block (quarter row)
#define NSEG (W / PXB)    // 4

// Fused deformable-conv kernel.
// Block = 32 consecutive pixels of one row of one image. 2048 blocks x 256 thr.
// Phase 1: 3x3 conv 128->8 (offsets), each thread: 2 pixels x 8 channels.
// Phase 1.5: LDS reduce over 16 channel groups + bias -> final offsets.
// Phase 2: bilinear sample, each thread: 1 pixel x 16 channels, coalesced
//          float2 stores of the 2x2 output block.
__global__ __launch_bounds__(256) void dcn_fused(
    const float* __restrict__ x, const float* __restrict__ wg,
    const float* __restrict__ b, float* __restrict__ out) {

  __shared__ float lacc[16][PXB][8];  // 16 KB partial conv accumulators
  __shared__ float loff[PXB][9];      // padded (stride 9) final offsets

  const int t = threadIdx.x;
  const int bx = blockIdx.x;
  const int seg = bx & (NSEG - 1);
  const int y = (bx >> 2) & (H - 1);
  const int n = bx >> 9;
  const int x0 = seg * PXB;

  const float* xn = x + (size_t)n * C * HW;

  // ---------------- Phase 1: partial offset conv ---------------------------
  {
    const int pp = t & 15;   // pixel pair -> pixels x0+2pp, x0+2pp+1
    const int cg = t >> 4;   // channel group 0..15 (8 channels each)
    const int xb = x0 + 2 * pp;

    // Hoisted boundary masks / clamped offsets (channel-invariant).
    int xs[4];
    float colm[4];
#pragma unroll
    for (int j = 0; j < 4; ++j) {
      int xa = xb - 1 + j;
      colm[j] = ((unsigned)xa < (unsigned)W) ? 1.f : 0.f;
      xs[j] = xa < 0 ? 0 : (xa > W - 1 ? W - 1 : xa);
    }
    int rowo[3];
    float m[3][4];
#pragma unroll
    for (int r = 0; r < 3; ++r) {
      int yy = y + r - 1;
      float rm = ((unsigned)yy < (unsigned)H) ? 1.f : 0.f;
      int yc = yy < 0 ? 0 : (yy > H - 1 ? H - 1 : yy);
      rowo[r] = yc * W;
#pragma unroll
      for (int j = 0; j < 4; ++j) m[r][j] = rm * colm[j];
    }

    float acc[2][8];
#pragma unroll
    for (int p = 0; p < 8; ++p) { acc[0][p] = 0.f; acc[1][p] = 0.f; }

    for (int c = 0; c < 8; ++c) {
      const int ch = cg * 8 + c;
      const float* xc = xn + (size_t)ch * HW;
      float xv[3][4];
#pragma unroll
      for (int r = 0; r < 3; ++r)
#pragma unroll
        for (int j = 0; j < 4; ++j)
          xv[r][j] = xc[rowo[r] + xs[j]] * m[r][j];

      const float* wc = wg + (size_t)ch * 9;  // + p*C*9 below (uniform -> s_load)
#pragma unroll
      for (int p = 0; p < 8; ++p) {
        const float* wp = wc + (size_t)p * C * 9;
#pragma unroll
        for (int r = 0; r < 3; ++r) {
#pragma unroll
          for (int kw = 0; kw < 3; ++kw) {
            const float wv = wp[r * 3 + kw];
            acc[0][p] += xv[r][kw] * wv;
            acc[1][p] += xv[r][kw + 1] * wv;
          }
        }
      }
    }
#pragma unroll
    for (int p = 0; p < 8; ++p) {
      lacc[cg][2 * pp][p] = acc[0][p];
      lacc[cg][2 * pp + 1][p] = acc[1][p];
    }
  }
  __syncthreads();

  // ---------------- Phase 1.5: reduce 16 groups + bias ---------------------
  {
    const int px = t >> 3;  // 0..31
    const int p = t & 7;
    float s = b[p];
#pragma unroll
    for (int g = 0; g < 16; ++g) s += lacc[g][px][p];
    loff[px][p] = s;
  }
  __syncthreads();

  // ---------------- Phase 2: bilinear sample + store -----------------------
  {
    const int px = t & (PXB - 1);
    const int sg = t >> 5;  // 0..7 (16 channels each)
    const int xx = x0 + px;

    float offv[8];
#pragma unroll
    for (int q = 0; q < 8; ++q) offv[q] = loff[px][q];

    int o00[4], o01[4], o10[4], o11[4];
    float w00[4], w01[4], w10[4], w11[4];
#pragma unroll
    for (int p = 0; p < 4; ++p) {
      float sy = (float)y + offv[2 * p];
      float sx = (float)xx + offv[2 * p + 1];
      float y0f = floorf(sy), x0f = floorf(sx);
      float wy1 = sy - y0f, wx1 = sx - x0f;
      float wy0 = 1.f - wy1, wx0 = 1.f - wx1;
      int iy0 = (int)y0f, ix0 = (int)x0f;
      int iy1 = iy0 + 1, ix1 = ix0 + 1;
      float vy0 = ((unsigned)iy0 < (unsigned)H) ? 1.f : 0.f;
      float vy1 = ((unsigned)iy1 < (unsigned)H) ? 1.f : 0.f;
      float vx0 = ((unsigned)ix0 < (unsigned)W) ? 1.f : 0.f;
      float vx1 = ((unsigned)ix1 < (unsigned)W) ? 1.f : 0.f;
      int cy0 = iy0 < 0 ? 0 : (iy0 > H - 1 ? H - 1 : iy0);
      int cy1 = iy1 < 0 ? 0 : (iy1 > H - 1 ? H - 1 : iy1);
      int cx0 = ix0 < 0 ? 0 : (ix0 > W - 1 ? W - 1 : ix0);
      int cx1 = ix1 < 0 ? 0 : (ix1 > W - 1 ? W - 1 : ix1);
      o00[p] = cy0 * W + cx0; o01[p] = cy0 * W + cx1;
      o10[p] = cy1 * W + cx0; o11[p] = cy1 * W + cx1;
      w00[p] = wy0 * wx0 * vy0 * vx0;
      w01[p] = wy0 * wx1 * vy0 * vx1;
      w10[p] = wy1 * wx0 * vy1 * vx0;
      w11[p] = wy1 * wx1 * vy1 * vx1;
    }

    float* outn = out + (size_t)n * C * (2 * H) * (2 * W);
    for (int c = sg * 16; c < sg * 16 + 16; ++c) {
      const float* xc = xn + (size_t)c * HW;
      float s[4];
#pragma unroll
      for (int p = 0; p < 4; ++p) {
        s[p] = w00[p] * xc[o00[p]] + w01[p] * xc[o01[p]] +
               w10[p] * xc[o10[p]] + w11[p] * xc[o11[p]];
      }
      float* oc = outn + (size_t)c * (2 * H) * (2 * W);
      float2* r0 = (float2*)(oc + (size_t)(2 * y) * (2 * W) + 2 * xx);
      float2* r1 = (float2*)(oc + (size_t)(2 * y + 1) * (2 * W) + 2 * xx);
      *r0 = make_float2(s[0], s[1]);
      *r1 = make_float2(s[2], s[3]);
    }
  }
}

extern "C" void kernel_launch(void* const* d_in, const int* in_sizes, int n_in,
                              void* d_out, int out_size, void* d_ws, size_t ws_size,
                              hipStream_t stream) {
  const float* x = (const float*)d_in[0];
  const float* w = (const float*)d_in[1];
  const float* b = (const float*)d_in[2];
  float* out = (float*)d_out;
  (void)d_ws; (void)ws_size;

  dim3 grid(NB * H * NSEG), block(256);
  dcn_fused<<<grid, block, 0, stream>>>(x, w, b, out);
}